// Round 1
// 163.101 us; speedup vs baseline: 1.1192x; 1.1192x over previous
//
#include <hip/hip_runtime.h>
#include <cstdint>

#define NPOS   32768   // B*H*W
#define KCODE  1024
#define DDIM   256

typedef unsigned long long u64;
typedef unsigned short u16;
typedef __attribute__((ext_vector_type(8))) short short8x;   // 8 bf16 (4 VGPR)
typedef __attribute__((ext_vector_type(4))) float f32x4;     // MFMA acc

__device__ __forceinline__ u16 bf16_rne(float x) {
  unsigned u = __float_as_uint(x);
  return (u16)((u + 0x7fffu + ((u >> 16) & 1u)) >> 16);
}
__device__ __forceinline__ float bf16_tof(u16 h) {
  return __uint_as_float(((unsigned)h) << 16);
}

// ---- kernel 0: pack W into MFMA-fragment-direct layout + wsq ---------------
// Virtual-K: 24 chunks of 32 vd; c 0..7 -> Wh (x Xh), 8..15 -> Wh (x Xl),
// 16..23 -> Wl (x Xh).
// Layout (short8x units): frag = ((kh*24 + c)*4 + cg)*8 + ct; entry frag*64 + lane,
// lane = g*16 + m holds W[code = kh*512+cg*128+ct*16+m][vd = g*8+e], e=0..7.
// => each A-frag load in argmin is one coalesced 1024B wave read. No W LDS.
__global__ void pack_w(const float* __restrict__ w, u16* __restrict__ Wp,
                       float* __restrict__ wsq) {
  const int t = threadIdx.x;              // 256 thr, 8 codes per block
  const int k = blockIdx.x * 8 + (t >> 5);
  const int sub = t & 31;                 // 32 threads per code
  const int g = sub & 3;
  const int dc = sub >> 2;                // d-chunk 0..7
  const int d0 = sub * 8;                 // = dc*32 + g*8
  float x[8];
  *(float4*)(x)     = *(const float4*)(w + (size_t)k * DDIM + d0);
  *(float4*)(x + 4) = *(const float4*)(w + (size_t)k * DDIM + d0 + 4);
  float s = 0.f;
  u16 h[8], lo[8];
  #pragma unroll
  for (int i = 0; i < 8; ++i) {
    s += x[i] * x[i];
    h[i] = bf16_rne(x[i]);
    lo[i] = bf16_rne(x[i] - bf16_tof(h[i]));
  }
  short8x hv, lv;
  #pragma unroll
  for (int i = 0; i < 8; ++i) { hv[i] = (short)h[i]; lv[i] = (short)lo[i]; }
  const int kh = k >> 9, cg = (k >> 7) & 3, ct = (k >> 4) & 7, m = k & 15;
  const int lane = g * 16 + m;
  #pragma unroll
  for (int r = 0; r < 3; ++r) {
    const int c = dc + r * 8;
    const size_t off =
        (((size_t)((kh * 24 + c) * 4 + cg) * 8 + ct) * 64 + lane) * 8;
    *(short8x*)(Wp + off) = (r < 2) ? hv : lv;
  }
  #pragma unroll
  for (int off = 16; off > 0; off >>= 1) s += __shfl_down(s, off, 32);
  if (sub == 0) wsq[k] = s;
}

// ---- kernel 0b: wt[d][k] = w[k][d] (for gather2) ---------------------------
__global__ void wt_kernel(const float* __restrict__ w, float* __restrict__ wt) {
  __shared__ float T[64][65];
  const int k0 = blockIdx.x * 64;
  const int d0 = blockIdx.y * 64;
  const int c = threadIdx.x & 63;
  const int r = threadIdx.x >> 6;
  #pragma unroll
  for (int p = 0; p < 16; ++p)
    T[p * 4 + r][c] = w[(size_t)(k0 + p * 4 + r) * DDIM + d0 + c];
  __syncthreads();
  #pragma unroll
  for (int p = 0; p < 16; ++p)
    wt[(size_t)(d0 + p * 4 + r) * KCODE + k0 + c] = T[c][p * 4 + r];
}

// ---- kernel 1: MFMA dist-GEMM + argmin -------------------------------------
// Grid 512 (XCD-swizzled) = 256 n-blocks x 2 k-halves. Block: 512 thr = 8 waves.
// Block covers 128 n x 512 codes. Wave (cg = wv>>1, nh = wv&1): 128 codes x 64 n,
// acc[8][4] = 128 VGPR. W frags: direct global->reg (no LDS, zero reuse anyway),
// double register set, prefetched 1 chunk ahead. X: z converted in-kernel into
// a linear frag-layout LDS dbuf (conflict-free write and read).
__global__ __launch_bounds__(512, 2) void argmin_mfma(
    const float* __restrict__ z, const u16* __restrict__ Wp,
    const float* __restrict__ wsq, u64* __restrict__ part) {
  __shared__ __align__(16) u16 Xs[2][8 * 64 * 8];   // 2 x 8 KB
  __shared__ u64 Red[8][64];

  const int tid = threadIdx.x;
  const int l = tid & 63, wv = tid >> 6;
  const int g = l >> 4;

  // bijective XCD swizzle: 512 wgs = 8 XCDs x 64 -> kh-pairs share an XCD's L2
  const int bid = blockIdx.x;
  const int swz = (bid & 7) * 64 + (bid >> 3);
  const int nb = swz >> 1, kh = swz & 1;
  const int cg = wv >> 1, nh = wv & 1;
  const int n0 = nb * 128;
  const int bimg = n0 >> 10, hw0 = n0 & 1023;
  const float* zb = z + (size_t)bimg * (DDIM * 1024) + hw0;

  // conversion role: this thread converts d-quad gs for position nl
  const int gs = cg;
  const int nl = nh * 64 + l;
  const int slot = ((nl >> 4) * 64 + gs * 16 + (nl & 15)) * 8;  // u16 idx

  // W frag pointer (short8x units): + c*2048 + ct*64
  const short8x* Wf = (const short8x*)Wp + (size_t)kh * 49152 + cg * 512 + l;
  // X frag read pointers: + nt*64
  const short8x* Xr0 = (const short8x*)&Xs[0][0] + (nh * 4) * 64 + l;
  const short8x* Xr1 = (const short8x*)&Xs[1][0] + (nh * 4) * 64 + l;

  f32x4 acc[8][4];
  #pragma unroll
  for (int ct = 0; ct < 8; ++ct)
    #pragma unroll
    for (int nt = 0; nt < 4; ++nt) acc[ct][nt] = (f32x4){0.f, 0.f, 0.f, 0.f};

  short8x afA[8], afB[8];
  float xv[8];

  // ---- prologue: W chunk 0 -> afA; convert z chunk 0 -> Xs[0] ----
  #pragma unroll
  for (int ct = 0; ct < 8; ++ct) afA[ct] = Wf[ct * 64];
  #pragma unroll
  for (int i = 0; i < 8; ++i)
    xv[i] = zb[(size_t)(gs * 8 + i) * 1024 + nl];
  {
    short8x xw;
    #pragma unroll
    for (int i = 0; i < 8; ++i) xw[i] = (short)bf16_rne(xv[i]);
    *(short8x*)(&Xs[0][slot]) = xw;
  }
  __syncthreads();

  #pragma unroll 1
  for (int c = 0; c < 24; c += 2) {
    // ---- even chunk c (afA, Xs[0]); prefetch c+1 ----
    {
      const int c1 = c + 1;
      #pragma unroll
      for (int ct = 0; ct < 8; ++ct) afB[ct] = Wf[c1 * 2048 + ct * 64];
      const int d1 = (c1 & 7) * 32 + gs * 8;
      #pragma unroll
      for (int i = 0; i < 8; ++i)
        xv[i] = zb[(size_t)(d1 + i) * 1024 + nl];
      short8x bf[4];
      #pragma unroll
      for (int nt = 0; nt < 4; ++nt) bf[nt] = Xr0[nt * 64];
      #pragma unroll
      for (int ct = 0; ct < 8; ++ct)
        #pragma unroll
        for (int nt = 0; nt < 4; ++nt)
          acc[ct][nt] = __builtin_amdgcn_mfma_f32_16x16x32_bf16(
              afA[ct], bf[nt], acc[ct][nt], 0, 0, 0);
      const bool isl = ((c1 >> 3) == 1);
      short8x xw;
      #pragma unroll
      for (int i = 0; i < 8; ++i) {
        u16 hh = bf16_rne(xv[i]);
        xw[i] = (short)(isl ? bf16_rne(xv[i] - bf16_tof(hh)) : hh);
      }
      *(short8x*)(&Xs[1][slot]) = xw;
      __syncthreads();
    }
    // ---- odd chunk c+1 (afB, Xs[1]); prefetch c+2 (wrap: harmless) ----
    {
      const int c2 = (c + 2 < 24) ? c + 2 : 0;
      #pragma unroll
      for (int ct = 0; ct < 8; ++ct) afA[ct] = Wf[c2 * 2048 + ct * 64];
      const int d2 = (c2 & 7) * 32 + gs * 8;
      #pragma unroll
      for (int i = 0; i < 8; ++i)
        xv[i] = zb[(size_t)(d2 + i) * 1024 + nl];
      short8x bf[4];
      #pragma unroll
      for (int nt = 0; nt < 4; ++nt) bf[nt] = Xr1[nt * 64];
      #pragma unroll
      for (int ct = 0; ct < 8; ++ct)
        #pragma unroll
        for (int nt = 0; nt < 4; ++nt)
          acc[ct][nt] = __builtin_amdgcn_mfma_f32_16x16x32_bf16(
              afB[ct], bf[nt], acc[ct][nt], 0, 0, 0);
      const bool isl = ((c2 >> 3) == 1);
      short8x xw;
      #pragma unroll
      for (int i = 0; i < 8; ++i) {
        u16 hh = bf16_rne(xv[i]);
        xw[i] = (short)(isl ? bf16_rne(xv[i] - bf16_tof(hh)) : hh);
      }
      *(short8x*)(&Xs[0][slot]) = xw;
      __syncthreads();
    }
  }

  // ---- epilogue: dist = wsq[k] - 2*dot, packed-key argmin ----
  const int cbase = kh * 512 + cg * 128;
  float4 wq[8];
  #pragma unroll
  for (int ct = 0; ct < 8; ++ct)
    wq[ct] = *(const float4*)(wsq + cbase + ct * 16 + g * 4);

  #pragma unroll
  for (int nt = 0; nt < 4; ++nt) {
    u64 best = ~0ull;
    #pragma unroll
    for (int ct = 0; ct < 8; ++ct) {
      const float* wqv = (const float*)&wq[ct];
      #pragma unroll
      for (int r = 0; r < 4; ++r) {
        // C/D layout: row(code) = g*4 + r, col(n) = m   [m89-verified]
        float dist = wqv[r] - 2.0f * acc[ct][nt][r];
        unsigned u = __float_as_uint(dist);
        u = (u & 0x80000000u) ? ~u : (u | 0x80000000u);  // monotone order
        u64 key = ((u64)u << 32) | (unsigned)(cbase + ct * 16 + g * 4 + r);
        best = best < key ? best : key;                  // ties -> smallest k
      }
    }
    u64 o = __shfl_xor(best, 16, 64); best = o < best ? o : best;
    o = __shfl_xor(best, 32, 64);     best = o < best ? o : best;
    if (l < 16) Red[wv][nt * 16 + l] = best;   // j = nt*16 + m
  }
  __syncthreads();
  if (tid < 128) {
    const int j = tid & 63, nh2 = tid >> 6;
    u64 b0 = Red[0 + nh2][j], b1 = Red[2 + nh2][j];
    u64 b2 = Red[4 + nh2][j], b3 = Red[6 + nh2][j];
    u64 mA = b0 < b1 ? b0 : b1;
    u64 mB = b2 < b3 ? b2 : b3;
    mA = mA < mB ? mA : mB;
    part[(size_t)kh * NPOS + n0 + tid] = mA;   // n_local = nh2*64 + j = tid
  }
}

// ---- kernel 1b: combine the two k-half partials ----------------------------
__global__ void combine_kernel(const u64* __restrict__ part, int* __restrict__ idx) {
  const int n = blockIdx.x * 256 + threadIdx.x;
  u64 a = part[n], b = part[NPOS + n];
  idx[n] = (int)((a < b ? a : b) & 0xffffffffull);
}

// ---- kernel 2: gather via LDS-resident w-slice (reads wt) ------------------
#define WPITCH 1028
__global__ __launch_bounds__(256) void gather2_kernel(
    const float* __restrict__ wt, const int* __restrict__ idx,
    float* __restrict__ out) {
  __shared__ __align__(16) float Ws[16 * WPITCH];
  const int tid = threadIdx.x;
  const int bimg = blockIdx.x >> 4;
  const int c0 = (blockIdx.x & 15) * 16;
  int4 kv = *(const int4*)(idx + bimg * 1024 + tid * 4);
  #pragma unroll
  for (int cc = 0; cc < 16; ++cc) {
    float4 v = *(const float4*)(wt + (size_t)(c0 + cc) * KCODE + tid * 4);
    *(float4*)(Ws + cc * WPITCH + tid * 4) = v;
  }
  __syncthreads();
  float* ob = out + (size_t)bimg * DDIM * 1024 + (size_t)c0 * 1024 + tid * 4;
  #pragma unroll
  for (int cc = 0; cc < 16; ++cc) {
    const float* wr = Ws + cc * WPITCH;
    float4 v;
    v.x = wr[kv.x]; v.y = wr[kv.y]; v.z = wr[kv.z]; v.w = wr[kv.w];
    *(float4*)(ob + (size_t)cc * 1024) = v;               // codes
    *(float4*)(ob + (size_t)cc * 1024 + 8388608) = v;     // codes_bar
  }
}

// fallback gather (no wt dependency)
__global__ void gather_kernel(const float* __restrict__ w, const int* __restrict__ idx,
                              float* __restrict__ out) {
  const int gi = blockIdx.x * 256 + threadIdx.x;
  const int hw4 = gi & 255;
  const int c = (gi >> 8) & 255;
  const int b = gi >> 16;
  int4 kv = *(const int4*)(idx + b * 1024 + hw4 * 4);
  float4 v;
  v.x = w[(size_t)kv.x * 256 + c];
  v.y = w[(size_t)kv.y * 256 + c];
  v.z = w[(size_t)kv.z * 256 + c];
  v.w = w[(size_t)kv.w * 256 + c];
  float4* o = (float4*)out;
  o[gi] = v;
  o[gi + 2097152] = v;
}

extern "C" void kernel_launch(void* const* d_in, const int* in_sizes, int n_in,
                              void* d_out, int out_size, void* d_ws, size_t ws_size,
                              hipStream_t stream) {
  const float* z = (const float*)d_in[0];   // [32,256,32,32] fp32
  const float* w = (const float*)d_in[1];   // [1024,256] fp32
  float* out = (float*)d_out;

  float* wsq = (float*)d_ws;                 // 4 KB @ 0
  int* idx = (int*)((char*)d_ws + 4096);     // 128 KB @ 4 KB
  const size_t need = 4096 + 131072 + 1048576;
  const bool ws_ok = ws_size >= need;
  float* wt = ws_ok ? (float*)((char*)d_ws + 4096 + 131072)
                    : out + (size_t)out_size - 262144;

  // Scratch in the codes_bar half of d_out (fully consumed before gather
  // overwrites it; stream-ordered): Wp 1.5 MB, partials 512 KB.
  u16* Wp   = (u16*)(out + 8388608);         // floats [8388608, 8781824)
  u64* part = (u64*)(out + 8781824);         // floats [8781824, 8912896)

  pack_w<<<128, 256, 0, stream>>>(w, Wp, wsq);
  wt_kernel<<<dim3(16, 4), 256, 0, stream>>>(w, wt);
  argmin_mfma<<<512, 512, 0, stream>>>(z, Wp, wsq, part);
  combine_kernel<<<NPOS / 256, 256, 0, stream>>>(part, idx);
  if (ws_ok)
    gather2_kernel<<<512, 256, 0, stream>>>(wt, idx, out);
  else
    gather_kernel<<<2097152 / 256, 256, 0, stream>>>(w, idx, out);
}

// Round 2
// 137.990 us; speedup vs baseline: 1.3229x; 1.1820x over previous
//
#include <hip/hip_runtime.h>
#include <cstdint>

#define NPOS   32768   // B*H*W
#define KCODE  1024
#define DDIM   256

typedef unsigned long long u64;
typedef unsigned short u16;
typedef __attribute__((ext_vector_type(8))) short short8x;   // 8 bf16 (4 VGPR)
typedef __attribute__((ext_vector_type(4))) float f32x4;     // MFMA acc

__device__ __forceinline__ u16 bf16_rne(float x) {
  unsigned u = __float_as_uint(x);
  return (u16)((u + 0x7fffu + ((u >> 16) & 1u)) >> 16);
}
__device__ __forceinline__ float bf16_tof(u16 h) {
  return __uint_as_float(((unsigned)h) << 16);
}

// ---- kernel 0: pack W into MFMA-fragment-direct layout + wsq ---------------
// Virtual-K: 24 chunks of 32 vd; c 0..7 -> Wh (x Xh), 8..15 -> Wh (x Xl),
// 16..23 -> Wl (x Xh).
// Layout (short8x units): frag = ((kh*24 + c)*4 + cg)*8 + ct; entry frag*64 + lane,
// lane = g*16 + m holds W[code = kh*512+cg*128+ct*16+m][vd = g*8+e], e=0..7.
// => each A-frag load in argmin is one coalesced 1024B wave read. No W LDS.
__global__ void pack_w(const float* __restrict__ w, u16* __restrict__ Wp,
                       float* __restrict__ wsq) {
  const int t = threadIdx.x;              // 256 thr, 8 codes per block
  const int k = blockIdx.x * 8 + (t >> 5);
  const int sub = t & 31;                 // 32 threads per code
  const int g = sub & 3;
  const int dc = sub >> 2;                // d-chunk 0..7
  const int d0 = sub * 8;                 // = dc*32 + g*8
  float x[8];
  *(float4*)(x)     = *(const float4*)(w + (size_t)k * DDIM + d0);
  *(float4*)(x + 4) = *(const float4*)(w + (size_t)k * DDIM + d0 + 4);
  float s = 0.f;
  u16 h[8], lo[8];
  #pragma unroll
  for (int i = 0; i < 8; ++i) {
    s += x[i] * x[i];
    h[i] = bf16_rne(x[i]);
    lo[i] = bf16_rne(x[i] - bf16_tof(h[i]));
  }
  short8x hv, lv;
  #pragma unroll
  for (int i = 0; i < 8; ++i) { hv[i] = (short)h[i]; lv[i] = (short)lo[i]; }
  const int kh = k >> 9, cg = (k >> 7) & 3, ct = (k >> 4) & 7, m = k & 15;
  const int lane = g * 16 + m;
  #pragma unroll
  for (int r = 0; r < 3; ++r) {
    const int c = dc + r * 8;
    const size_t off =
        (((size_t)((kh * 24 + c) * 4 + cg) * 8 + ct) * 64 + lane) * 8;
    *(short8x*)(Wp + off) = (r < 2) ? hv : lv;
  }
  #pragma unroll
  for (int off = 16; off > 0; off >>= 1) s += __shfl_down(s, off, 32);
  if (sub == 0) wsq[k] = s;
}

// ---- kernel 0b: wt[d][k] = w[k][d] (for gather2) ---------------------------
__global__ void wt_kernel(const float* __restrict__ w, float* __restrict__ wt) {
  __shared__ float T[64][65];
  const int k0 = blockIdx.x * 64;
  const int d0 = blockIdx.y * 64;
  const int c = threadIdx.x & 63;
  const int r = threadIdx.x >> 6;
  #pragma unroll
  for (int p = 0; p < 16; ++p)
    T[p * 4 + r][c] = w[(size_t)(k0 + p * 4 + r) * DDIM + d0 + c];
  __syncthreads();
  #pragma unroll
  for (int p = 0; p < 16; ++p)
    wt[(size_t)(d0 + p * 4 + r) * KCODE + k0 + c] = T[c][p * 4 + r];
}

// ---- kernel 1: MFMA dist-GEMM + argmin -------------------------------------
// Grid 256 = 1 block/CU, 512 thr = 8 waves. Block: ALL 1024 codes x 128 n.
// Prologue converts the block's z slice (128 n x 256 d) once into a 128 KB
// LDS hi/lo frag buffer -> the K-loop has ZERO barriers: per chunk each wave
// does {4 W-frag global loads (reg-dbuf, 1 chunk ahead), 8 ds_read_b128,
// 32 MFMA}. Wave tile: 64 codes x 128 n (acc[4][8] = 128 VGPR). kh halves run
// sequentially per block, merged in Red -> idx written directly (no combine).
__global__ __launch_bounds__(512, 2) void argmin_mfma(
    const float* __restrict__ z, const u16* __restrict__ Wp,
    const float* __restrict__ wsq, int* __restrict__ idx) {
  // X frags (short8x units): slot = hl*4096 + (dc*8 + nt)*64 + lane
  __shared__ __align__(16) u16 Xs[2 * 8 * 8 * 64 * 8];   // 128 KB
  __shared__ u64 Red[8][128];                            // 8 KB

  const int tid = threadIdx.x;
  const int l = tid & 63, wv = tid >> 6;
  const int g = l >> 4;

  // XCD swizzle: 256 wgs = 8 XCDs x 32 -> contiguous n-range per XCD's L2
  const int bid = blockIdx.x;
  const int nb = (bid & 7) * 32 + (bid >> 3);
  const int n0 = nb * 128;
  const int bimg = n0 >> 10, hw0 = n0 & 1023;
  const float* zb = z + (size_t)bimg * (DDIM * 1024) + hw0;

  // ---- prologue: convert z slice (128 n x 256 d) -> bf16 hi/lo frags ----
  #pragma unroll
  for (int rr = 0; rr < 8; ++rr) {
    const int id = rr * 512 + tid;
    const int gg = id >> 7;        // d-group 0..31 (8 d each)
    const int nl = id & 127;       // local n (lane-contiguous -> coalesced)
    float x[8];
    #pragma unroll
    for (int e = 0; e < 8; ++e)
      x[e] = zb[(size_t)(gg * 8 + e) * 1024 + nl];
    short8x hv, lv;
    #pragma unroll
    for (int e = 0; e < 8; ++e) {
      u16 hh = bf16_rne(x[e]);
      hv[e] = (short)hh;
      lv[e] = (short)bf16_rne(x[e] - bf16_tof(hh));
    }
    const int dc = gg >> 2, gq = gg & 3;
    const int nt = nl >> 4, mm = nl & 15;
    const int slot = (dc * 8 + nt) * 64 + gq * 16 + mm;   // short8x units
    *(short8x*)(&Xs[(size_t)slot * 8]) = hv;
    *(short8x*)(&Xs[(size_t)(slot + 4096) * 8]) = lv;
  }
  __syncthreads();   // the ONLY barrier before the epilogue

  // W frag base (short8x units): wave owns codes kh*512 + wv*64 .. +64
  // pack_w frag = ((kh*24 + c)*4 + cg)*8 + ctp; cg = wv>>1, ctp = (wv&1)*4 + ct
  const short8x* WfBase =
      (const short8x*)Wp + ((wv >> 1) * 8 + (wv & 1) * 4) * 64 + l;

  #pragma unroll 1
  for (int khp = 0; khp < 2; ++khp) {
    const short8x* Wf = WfBase + (size_t)khp * 49152;

    f32x4 acc[4][8];
    #pragma unroll
    for (int ct = 0; ct < 4; ++ct)
      #pragma unroll
      for (int nt = 0; nt < 8; ++nt) acc[ct][nt] = (f32x4){0.f, 0.f, 0.f, 0.f};

    short8x afA[4], afB[4];
    #pragma unroll
    for (int ct = 0; ct < 4; ++ct) afA[ct] = Wf[ct * 64];

    #pragma unroll 1
    for (int c = 0; c < 24; c += 2) {
      // ---- chunk c (afA); prefetch c+1 -> afB ----
      {
        #pragma unroll
        for (int ct = 0; ct < 4; ++ct)
          afB[ct] = Wf[(c + 1) * 2048 + ct * 64];
        const short8x* Xr = (const short8x*)Xs +
            (((c >> 3) == 1) ? 4096 : 0) + (c & 7) * 512 + l;
        short8x bf[8];
        #pragma unroll
        for (int nt = 0; nt < 8; ++nt) bf[nt] = Xr[nt * 64];
        __builtin_amdgcn_s_setprio(1);
        #pragma unroll
        for (int nt = 0; nt < 8; ++nt)
          #pragma unroll
          for (int ct = 0; ct < 4; ++ct)
            acc[ct][nt] = __builtin_amdgcn_mfma_f32_16x16x32_bf16(
                afA[ct], bf[nt], acc[ct][nt], 0, 0, 0);
        __builtin_amdgcn_s_setprio(0);
      }
      // ---- chunk c+1 (afB); prefetch c+2 -> afA (wrap: harmless reload) ----
      {
        const int c2 = (c + 2 < 24) ? c + 2 : 0;
        #pragma unroll
        for (int ct = 0; ct < 4; ++ct)
          afA[ct] = Wf[c2 * 2048 + ct * 64];
        const int c1 = c + 1;
        const short8x* Xr = (const short8x*)Xs +
            (((c1 >> 3) == 1) ? 4096 : 0) + (c1 & 7) * 512 + l;
        short8x bf[8];
        #pragma unroll
        for (int nt = 0; nt < 8; ++nt) bf[nt] = Xr[nt * 64];
        __builtin_amdgcn_s_setprio(1);
        #pragma unroll
        for (int nt = 0; nt < 8; ++nt)
          #pragma unroll
          for (int ct = 0; ct < 4; ++ct)
            acc[ct][nt] = __builtin_amdgcn_mfma_f32_16x16x32_bf16(
                afB[ct], bf[nt], acc[ct][nt], 0, 0, 0);
        __builtin_amdgcn_s_setprio(0);
      }
    }

    // ---- epilogue khp: dist = wsq[k] - 2*dot, packed-key argmin ----
    const int cbase = khp * 512 + wv * 64;
    float4 wq[4];
    #pragma unroll
    for (int ct = 0; ct < 4; ++ct)
      wq[ct] = *(const float4*)(wsq + cbase + ct * 16 + g * 4);

    #pragma unroll
    for (int nt = 0; nt < 8; ++nt) {
      u64 best = ~0ull;
      #pragma unroll
      for (int ct = 0; ct < 4; ++ct) {
        const float* wqv = (const float*)&wq[ct];
        #pragma unroll
        for (int r = 0; r < 4; ++r) {
          // C/D layout: row(code) = g*4 + r, col(n) = m   [m89-verified]
          float dist = wqv[r] - 2.0f * acc[ct][nt][r];
          unsigned u = __float_as_uint(dist);
          u = (u & 0x80000000u) ? ~u : (u | 0x80000000u);  // monotone order
          u64 key = ((u64)u << 32) | (unsigned)(cbase + ct * 16 + g * 4 + r);
          best = best < key ? best : key;                  // ties -> smallest k
        }
      }
      u64 o = __shfl_xor(best, 16, 64); best = o < best ? o : best;
      o = __shfl_xor(best, 32, 64);     best = o < best ? o : best;
      if (l < 16) {
        const int j = nt * 16 + l;
        if (khp == 0) Red[wv][j] = best;
        else { u64 p = Red[wv][j]; Red[wv][j] = best < p ? best : p; }
      }
    }
  }

  __syncthreads();
  if (tid < 128) {
    u64 best = Red[0][tid];
    #pragma unroll
    for (int w = 1; w < 8; ++w) {
      u64 o = Red[w][tid];
      best = o < best ? o : best;
    }
    idx[n0 + tid] = (int)(best & 0xffffffffull);
  }
}

// ---- kernel 2: gather via LDS-resident w-slice (reads wt) ------------------
#define WPITCH 1028
__global__ __launch_bounds__(256) void gather2_kernel(
    const float* __restrict__ wt, const int* __restrict__ idx,
    float* __restrict__ out) {
  __shared__ __align__(16) float Ws[16 * WPITCH];
  const int tid = threadIdx.x;
  const int bimg = blockIdx.x >> 4;
  const int c0 = (blockIdx.x & 15) * 16;
  int4 kv = *(const int4*)(idx + bimg * 1024 + tid * 4);
  #pragma unroll
  for (int cc = 0; cc < 16; ++cc) {
    float4 v = *(const float4*)(wt + (size_t)(c0 + cc) * KCODE + tid * 4);
    *(float4*)(Ws + cc * WPITCH + tid * 4) = v;
  }
  __syncthreads();
  float* ob = out + (size_t)bimg * DDIM * 1024 + (size_t)c0 * 1024 + tid * 4;
  #pragma unroll
  for (int cc = 0; cc < 16; ++cc) {
    const float* wr = Ws + cc * WPITCH;
    float4 v;
    v.x = wr[kv.x]; v.y = wr[kv.y]; v.z = wr[kv.z]; v.w = wr[kv.w];
    *(float4*)(ob + (size_t)cc * 1024) = v;               // codes
    *(float4*)(ob + (size_t)cc * 1024 + 8388608) = v;     // codes_bar
  }
}

// fallback gather (no wt dependency)
__global__ void gather_kernel(const float* __restrict__ w, const int* __restrict__ idx,
                              float* __restrict__ out) {
  const int gi = blockIdx.x * 256 + threadIdx.x;
  const int hw4 = gi & 255;
  const int c = (gi >> 8) & 255;
  const int b = gi >> 16;
  int4 kv = *(const int4*)(idx + b * 1024 + hw4 * 4);
  float4 v;
  v.x = w[(size_t)kv.x * 256 + c];
  v.y = w[(size_t)kv.y * 256 + c];
  v.z = w[(size_t)kv.z * 256 + c];
  v.w = w[(size_t)kv.w * 256 + c];
  float4* o = (float4*)out;
  o[gi] = v;
  o[gi + 2097152] = v;
}

extern "C" void kernel_launch(void* const* d_in, const int* in_sizes, int n_in,
                              void* d_out, int out_size, void* d_ws, size_t ws_size,
                              hipStream_t stream) {
  const float* z = (const float*)d_in[0];   // [32,256,32,32] fp32
  const float* w = (const float*)d_in[1];   // [1024,256] fp32
  float* out = (float*)d_out;

  float* wsq = (float*)d_ws;                 // 4 KB @ 0
  int* idx = (int*)((char*)d_ws + 4096);     // 128 KB @ 4 KB
  const size_t need = 4096 + 131072 + 1048576;
  const bool ws_ok = ws_size >= need;
  float* wt = ws_ok ? (float*)((char*)d_ws + 4096 + 131072)
                    : out + (size_t)out_size - 262144;

  // Scratch in the codes_bar half of d_out (fully consumed before gather
  // overwrites it; stream-ordered): Wp 1.5 MB.
  u16* Wp = (u16*)(out + 8388608);           // floats [8388608, 8781824)

  pack_w<<<128, 256, 0, stream>>>(w, Wp, wsq);
  wt_kernel<<<dim3(16, 4), 256, 0, stream>>>(w, wt);
  argmin_mfma<<<256, 512, 0, stream>>>(z, Wp, wsq, idx);
  if (ws_ok)
    gather2_kernel<<<512, 256, 0, stream>>>(wt, idx, out);
  else
    gather_kernel<<<2097152 / 256, 256, 0, stream>>>(w, idx, out);
}